// Round 3
// baseline (545.797 us; speedup 1.0000x reference)
//
#include <hip/hip_runtime.h>

typedef _Float16 half8 __attribute__((ext_vector_type(8)));
typedef float floatx4 __attribute__((ext_vector_type(4)));

#define T_STEPS 256
#define BB      16
#define NTH     512
#define RING_W  16

// d_ws layout (halves for weights/ring, bytes for flags)
#define WHH0_H  0
#define WIH1_H  65536
#define WHH1_H  131072
#define WIH0_H  196608
#define RING_H  229376              // byte offset 458752
#define FLAG_B  4653056             // 458752 + 64*16*4096
#define FLAG_BYTES 16384

__device__ __forceinline__ float sig_(float z)  { return __builtin_amdgcn_rcpf(1.f + __expf(-z)); }
__device__ __forceinline__ float tanh_(float z) { return 1.f - 2.f * __builtin_amdgcn_rcpf(1.f + __expf(2.f * z)); }

// Build fp16 MFMA B-fragment arrays.
// Frag index: ((wv*4+gi)*4+ks)*64 + lane ; lane holds W[gi*128+wv*16+(l&15)][ks*32+(l>>4)*8 + j]
__global__ __launch_bounds__(256) void prep_weights(
    const float* __restrict__ w_ih0, const float* __restrict__ w_hh0,
    const float* __restrict__ w_ih1, const float* __restrict__ w_hh1,
    _Float16* __restrict__ wf)
{
    const int idx = blockIdx.x * 256 + threadIdx.x;   // 0..8191
    const int l  = idx & 63;
    const int ks = (idx >> 6) & 3;
    const int gi = (idx >> 8) & 3;
    const int wv = (idx >> 10) & 7;
    const int row = gi * 128 + wv * 16 + (l & 15);
    const int kb  = ks * 32 + (l >> 4) * 8;
#pragma unroll
    for (int j = 0; j < 8; ++j) {
        wf[WHH0_H + idx * 8 + j] = (_Float16)w_hh0[row * 128 + kb + j];
        wf[WIH1_H + idx * 8 + j] = (_Float16)w_ih1[row * 128 + kb + j];
        wf[WHH1_H + idx * 8 + j] = (_Float16)w_hh1[row * 128 + kb + j];
    }
    if (ks == 0) {
        // x-frag convention: lk=0 holds x[k=0..7] (w = W[0..7]);
        // lk=1 holds x[k=6..13] (w = 0,0,W[8..13]); lk>=2 weights 0.
        const int lk = l >> 4;
        const int oi = ((wv * 4 + gi) * 64 + l) * 8;
#pragma unroll
        for (int j = 0; j < 8; ++j) {
            float v = 0.f;
            if (lk == 0)                v = w_ih0[row * 14 + j];
            else if (lk == 1 && j >= 2) v = w_ih0[row * 14 + 6 + j];
            wf[WIH0_H + oi + j] = (_Float16)v;
        }
    }
}

__global__ __launch_bounds__(NTH) void lstm2_pipe(
    const float* __restrict__ x, const _Float16* __restrict__ wf,
    const float* __restrict__ b_ih0, const float* __restrict__ b_hh0,
    const float* __restrict__ b_ih1, const float* __restrict__ b_hh1,
    const float* __restrict__ w_lin, const float* __restrict__ b_lin,
    float* __restrict__ out, char* __restrict__ wsb)
{
    __shared__ __align__(16) _Float16 hbuf[2][BB * 128];   // 8 KB, XOR-swizzled

    const int tid  = threadIdx.x;
    const int l    = tid & 63;
    const int wv   = tid >> 6;
    const int lrow = l & 15;
    const int lk   = l >> 4;
    const int bid  = blockIdx.x;
    // pair producer (role 0) and consumer (role 1) of a group 8 apart -> same XCD
    const int pos  = bid & 7;
    const int role = (bid >> 3) & 1;
    const int g    = (bid >> 4) * 8 + pos;
    const int b0   = g * BB;

    _Float16* ring = (_Float16*)wsb + RING_H + (size_t)g * RING_W * 2048;
    int* flag_p = (int*)(wsb + FLAG_B) + g * 64;
    int* flag_c = flag_p + 32;

    for (int i = tid; i < 1024; i += NTH) ((unsigned*)hbuf[1])[i] = 0u;

    const half8* wsf = (const half8*)wf;

    if (role == 0) {
        // ---------------- producer: layer 1 ----------------
        half8 whh0f[16], wih0f[4];
#pragma unroll
        for (int gi = 0; gi < 4; ++gi) {
#pragma unroll
            for (int ks = 0; ks < 4; ++ks)
                whh0f[gi * 4 + ks] = wsf[WHH0_H / 8 + ((wv * 4 + gi) * 4 + ks) * 64 + l];
            wih0f[gi] = wsf[WIH0_H / 8 + (wv * 4 + gi) * 64 + l];
        }
        float bias1[4];
#pragma unroll
        for (int gi = 0; gi < 4; ++gi) {
            const int col = gi * 128 + wv * 16 + lrow;
            bias1[gi] = b_ih0[col] + b_hh0[col];
        }
        float c1[4] = {0.f, 0.f, 0.f, 0.f};

        const int coff = (lk == 1) ? 6 : 0;
        const float* xp = x + (size_t)(b0 + lrow) * (T_STEPS * 14) + coff;
        float xr[8];
#pragma unroll
        for (int j = 0; j < 8; ++j) xr[j] = xp[j];
        int seen_c = 0;
        __syncthreads();

        for (int t = 0; t < T_STEPS; ++t) {
            const int cur = t & 1, prv = cur ^ 1;
            half8 xh;
#pragma unroll
            for (int j = 0; j < 8; ++j) xh[j] = (_Float16)xr[j];
            if (t + 1 < T_STEPS) {
#pragma unroll
                for (int j = 0; j < 8; ++j) xr[j] = xp[(t + 1) * 14 + j];
            }
            const char* hrd = (const char*)hbuf[prv];
            half8 h1p[4];
#pragma unroll
            for (int ks = 0; ks < 4; ++ks) {
                const int off = lrow * 256 + ((ks * 64 + lk * 16) ^ ((lrow & 7) << 4));
                h1p[ks] = *(const half8*)(hrd + off);
            }
            floatx4 acc[4];
#pragma unroll
            for (int gi = 0; gi < 4; ++gi) {
                acc[gi] = (floatx4){bias1[gi], bias1[gi], bias1[gi], bias1[gi]};
                acc[gi] = __builtin_amdgcn_mfma_f32_16x16x32_f16(xh, wih0f[gi], acc[gi], 0, 0, 0);
#pragma unroll
                for (int ks = 0; ks < 4; ++ks)
                    acc[gi] = __builtin_amdgcn_mfma_f32_16x16x32_f16(h1p[ks], whh0f[gi * 4 + ks], acc[gi], 0, 0, 0);
            }
            // ring backpressure (rarely spins; cached seen_c)
            if (t >= RING_W && tid == 0) {
                while (seen_c < t - (RING_W - 1)) {
                    seen_c = __hip_atomic_load(flag_c, __ATOMIC_RELAXED, __HIP_MEMORY_SCOPE_AGENT);
                    if (seen_c < t - (RING_W - 1)) __builtin_amdgcn_s_sleep(2);
                }
            }
            __syncthreads();   // orders spin -> ring writes
            char* hwr = (char*)hbuf[cur];
            _Float16* rt = ring + (size_t)(t & (RING_W - 1)) * 2048;
            const int u = wv * 16 + lrow;
#pragma unroll
            for (int r = 0; r < 4; ++r) {
                const float ig = sig_(acc[0][r]);
                const float fg = sig_(acc[1][r]);
                const float gg = tanh_(acc[2][r]);
                const float og = sig_(acc[3][r]);
                c1[r] = fg * c1[r] + ig * gg;
                const float hv = og * tanh_(c1[r]);
                const int b = lk * 4 + r;
                const _Float16 hh = (_Float16)hv;
                *(_Float16*)(hwr + b * 256 + ((u * 2) ^ ((b & 7) << 4))) = hh;
                rt[b * 128 + u] = hh;
            }
            __syncthreads();   // drains LDS + ring stores (all waves)
            if (tid == 0)
                __hip_atomic_store(flag_p, t + 1, __ATOMIC_RELEASE, __HIP_MEMORY_SCOPE_AGENT);
        }
    } else {
        // ---------------- consumer: layer 2 ----------------
        half8 wih1f[16], whh1f[16];
#pragma unroll
        for (int gi = 0; gi < 4; ++gi)
#pragma unroll
            for (int ks = 0; ks < 4; ++ks) {
                const int idx = ((wv * 4 + gi) * 4 + ks) * 64 + l;
                wih1f[gi * 4 + ks] = wsf[WIH1_H / 8 + idx];
                whh1f[gi * 4 + ks] = wsf[WHH1_H / 8 + idx];
            }
        float bias2[4];
#pragma unroll
        for (int gi = 0; gi < 4; ++gi) {
            const int col = gi * 128 + wv * 16 + lrow;
            bias2[gi] = b_ih1[col] + b_hh1[col];
        }
        float c2[4] = {0.f, 0.f, 0.f, 0.f};
        int seen_p = 0;
        const int toff = lrow * 128 + lk * 8;   // A-frag offset within a ring tile (halves)

        __syncthreads();
        // prologue: wait for tiles 0,1 and prefetch into regs
        if (tid == 0) {
            while (seen_p < 2) {
                seen_p = __hip_atomic_load(flag_p, __ATOMIC_ACQUIRE, __HIP_MEMORY_SCOPE_AGENT);
                if (seen_p < 2) __builtin_amdgcn_s_sleep(2);
            }
        }
        __syncthreads();
        half8 h1nA[4], h1nB[4];
#pragma unroll
        for (int ks = 0; ks < 4; ++ks) h1nA[ks] = *(const half8*)(ring + toff + ks * 32);
#pragma unroll
        for (int ks = 0; ks < 4; ++ks) h1nB[ks] = *(const half8*)(ring + 2048 + toff + ks * 32);

#define CSTEP(T, H1N, CUR)                                                          \
        {                                                                           \
            const char* hrd = (const char*)hbuf[(CUR) ^ 1];                         \
            half8 h2p[4];                                                           \
            _Pragma("unroll")                                                       \
            for (int ks = 0; ks < 4; ++ks) {                                        \
                const int off = lrow * 256 + ((ks * 64 + lk * 16) ^ ((lrow & 7) << 4)); \
                h2p[ks] = *(const half8*)(hrd + off);                               \
            }                                                                       \
            floatx4 acc[4];                                                         \
            _Pragma("unroll")                                                       \
            for (int gi = 0; gi < 4; ++gi) {                                        \
                acc[gi] = (floatx4){bias2[gi], bias2[gi], bias2[gi], bias2[gi]};    \
                _Pragma("unroll")                                                   \
                for (int ks = 0; ks < 4; ++ks) {                                    \
                    acc[gi] = __builtin_amdgcn_mfma_f32_16x16x32_f16(h2p[ks], whh1f[gi * 4 + ks], acc[gi], 0, 0, 0); \
                    acc[gi] = __builtin_amdgcn_mfma_f32_16x16x32_f16(H1N[ks], wih1f[gi * 4 + ks], acc[gi], 0, 0, 0); \
                }                                                                   \
            }                                                                       \
            char* hwr = (char*)hbuf[CUR];                                           \
            const int u = wv * 16 + lrow;                                           \
            _Pragma("unroll")                                                       \
            for (int r = 0; r < 4; ++r) {                                           \
                const float ig = sig_(acc[0][r]);                                   \
                const float fg = sig_(acc[1][r]);                                   \
                const float gg = tanh_(acc[2][r]);                                  \
                const float og = sig_(acc[3][r]);                                   \
                c2[r] = fg * c2[r] + ig * gg;                                       \
                const float hv = og * tanh_(c2[r]);                                 \
                const int b = lk * 4 + r;                                           \
                *(_Float16*)(hwr + b * 256 + ((u * 2) ^ ((b & 7) << 4))) = (_Float16)hv; \
            }                                                                       \
            if ((T) < T_STEPS - 2 && tid == 0) {                                    \
                while (seen_p < (T) + 3) {                                          \
                    seen_p = __hip_atomic_load(flag_p, __ATOMIC_ACQUIRE, __HIP_MEMORY_SCOPE_AGENT); \
                    if (seen_p < (T) + 3) __builtin_amdgcn_s_sleep(2);              \
                }                                                                   \
            }                                                                       \
            __syncthreads();                                                        \
            if ((T) < T_STEPS - 2) {                                                \
                const _Float16* rt = ring + (size_t)((((T) + 2) & (RING_W - 1))) * 2048; \
                _Pragma("unroll")                                                   \
                for (int ks = 0; ks < 4; ++ks)                                      \
                    H1N[ks] = *(const half8*)(rt + toff + ks * 32);                 \
            }                                                                       \
            if (tid == 0)                                                           \
                __hip_atomic_store(flag_c, (T) + 2, __ATOMIC_RELAXED, __HIP_MEMORY_SCOPE_AGENT); \
        }

        for (int t = 0; t < T_STEPS; t += 2) {
            CSTEP(t,     h1nA, 0);
            CSTEP(t + 1, h1nB, 1);
        }
#undef CSTEP

        // epilogue: out[b] = h2(255)[b] . w_lin + b_lin ; h2(255) in hbuf[1]
        if (tid < BB) {
            const char* hb = (const char*)hbuf[1];
            float acc = b_lin[0];
            for (int j = 0; j < 128; ++j) {
                const int off = tid * 256 + ((j * 2) ^ ((tid & 7) << 4));
                acc += w_lin[j] * (float)(*(const _Float16*)(hb + off));
            }
            out[b0 + tid] = acc;
        }
    }
}

extern "C" void kernel_launch(void* const* d_in, const int* in_sizes, int n_in,
                              void* d_out, int out_size, void* d_ws, size_t ws_size,
                              hipStream_t stream) {
    (void)in_sizes; (void)n_in; (void)ws_size; (void)out_size;
    const float* x     = (const float*)d_in[0];
    const float* w_ih0 = (const float*)d_in[1];
    const float* w_hh0 = (const float*)d_in[2];
    const float* b_ih0 = (const float*)d_in[3];
    const float* b_hh0 = (const float*)d_in[4];
    const float* w_ih1 = (const float*)d_in[5];
    const float* w_hh1 = (const float*)d_in[6];
    const float* b_ih1 = (const float*)d_in[7];
    const float* b_hh1 = (const float*)d_in[8];
    const float* w_lin = (const float*)d_in[9];
    const float* b_lin = (const float*)d_in[10];
    float* out = (float*)d_out;
    char* wsb = (char*)d_ws;

    hipMemsetAsync(wsb + FLAG_B, 0, FLAG_BYTES, stream);
    hipLaunchKernelGGL(prep_weights, dim3(32), dim3(256), 0, stream,
                       w_ih0, w_hh0, w_ih1, w_hh1, (_Float16*)d_ws);
    hipLaunchKernelGGL(lstm2_pipe, dim3(128), dim3(NTH), 0, stream,
                       x, (_Float16*)d_ws, b_ih0, b_hh0, b_ih1, b_hh1,
                       w_lin, b_lin, out, wsb);
}